// Round 5
// baseline (3127.292 us; speedup 1.0000x reference)
//
#include <hip/hip_runtime.h>
#include <stdint.h>

typedef __attribute__((ext_vector_type(8))) short bf16x8;
typedef __attribute__((ext_vector_type(4))) float f32x4;

#define BN 192  // dst nodes per bucket (192*68*4B LDS acc = 52 KB)

static __device__ __forceinline__ float b2f_lo(uint32_t w) {
  union { uint32_t u; float f; } c; c.u = w << 16; return c.f;
}
static __device__ __forceinline__ float b2f_hi(uint32_t w) {
  union { uint32_t u; float f; } c; c.u = w & 0xffff0000u; return c.f;
}
static __device__ __forceinline__ uint16_t f2b(float f) {
  union { float f; uint32_t u; } c; c.f = f;
  return (uint16_t)((c.u + 0x7fffu + ((c.u >> 16) & 1u)) >> 16);
}

static __device__ __forceinline__ f32x4 load4f(const float* p) {
  return *(const f32x4*)p;
}
static __device__ __forceinline__ f32x4 load4f(const uint16_t* p) {
  uint2 t = *(const uint2*)p;
  f32x4 r;
  r.x = b2f_lo(t.x); r.y = b2f_hi(t.x);
  r.z = b2f_lo(t.y); r.w = b2f_hi(t.y);
  return r;
}

static __device__ __forceinline__ bf16x8 load8b(const float* p) {
  f32x4 a = *(const f32x4*)p;
  f32x4 b = *(const f32x4*)(p + 4);
  bf16x8 r;
  r[0] = (short)f2b(a.x); r[1] = (short)f2b(a.y);
  r[2] = (short)f2b(a.z); r[3] = (short)f2b(a.w);
  r[4] = (short)f2b(b.x); r[5] = (short)f2b(b.y);
  r[6] = (short)f2b(b.z); r[7] = (short)f2b(b.w);
  return r;
}
static __device__ __forceinline__ bf16x8 load8b(const uint16_t* p) {
  return *(const bf16x8*)p;
}

// ---------------- bucket histogram over dst (both relations) ----------------
__global__ __launch_bounds__(256) void bucket_hist_kernel(
    const int* __restrict__ pt_dst, const int* __restrict__ tp_dst,
    int* __restrict__ bucketCount, int E, int NP, int NB) {
  extern __shared__ int hist[];
  int t = threadIdx.x;
  for (int b = t; b < NB; b += 256) hist[b] = 0;
  __syncthreads();
  long total = 2L * E;
  long stride = (long)gridDim.x * 256;
  for (long e = (long)blockIdx.x * 256 + t; e < total; e += stride) {
    int dstG = (e < E) ? (NP + pt_dst[e]) : tp_dst[e - E];
    atomicAdd(&hist[dstG / BN], 1);
  }
  __syncthreads();
  for (int b = t; b < NB; b += 256) {
    int h = hist[b];
    if (h > 0) atomicAdd(&bucketCount[b], h);
  }
}

// ---------------- exclusive scan of bucket counts (1 block) -----------------
__global__ __launch_bounds__(1024) void bucket_scan_kernel(
    const int* __restrict__ bucketCount, int* __restrict__ bucketStart,
    int* __restrict__ gCursor, int NB) {
  __shared__ int s[1024];
  int t = threadIdx.x;
  int K = (NB + 1023) >> 10;
  int b0 = t * K;
  int local = 0;
  for (int j = 0; j < K; ++j) {
    int b = b0 + j;
    if (b < NB) local += bucketCount[b];
  }
  int acc = local;
  s[t] = local;
  __syncthreads();
  for (int off = 1; off < 1024; off <<= 1) {
    int u = (t >= off) ? s[t - off] : 0;
    __syncthreads();
    acc += u;
    s[t] = acc;
    __syncthreads();
  }
  int run = acc - local;  // exclusive prefix of this thread's chunk
  for (int j = 0; j < K; ++j) {
    int b = b0 + j;
    if (b < NB) {
      bucketStart[b] = run;
      gCursor[b] = run;
      run += bucketCount[b];
    }
  }
}

// ---------------- partition: pk[slot] = (dl<<20)|srcGlobal ------------------
// chunked two-phase multi-split: local hist -> reserve ranges -> write.
__global__ __launch_bounds__(512) void partition_kernel(
    const int* __restrict__ pt_src, const int* __restrict__ pt_dst,
    const int* __restrict__ tp_src, const int* __restrict__ tp_dst,
    int* __restrict__ gCursor, uint32_t* __restrict__ pk,
    int E, int NP, int NB, int chunk) {
  extern __shared__ int lds[];
  int* hist = lds;        // [NB]
  int* base = lds + NB;   // [NB]
  int t = threadIdx.x;
  long e0 = (long)blockIdx.x * chunk;
  long e1 = e0 + chunk;
  long total = 2L * E;
  if (e1 > total) e1 = total;
  for (int b = t; b < NB; b += 512) hist[b] = 0;
  __syncthreads();
  for (long e = e0 + t; e < e1; e += 512) {
    int dstG = (e < E) ? (NP + pt_dst[e]) : tp_dst[e - E];
    atomicAdd(&hist[dstG / BN], 1);
  }
  __syncthreads();
  for (int b = t; b < NB; b += 512) {
    int h = hist[b];
    base[b] = (h > 0) ? atomicAdd(&gCursor[b], h) : 0;
    hist[b] = 0;  // reuse as local cursor
  }
  __syncthreads();
  for (long e = e0 + t; e < e1; e += 512) {
    int dstG, src;
    if (e < E) {
      dstG = NP + pt_dst[e];
      src = pt_src[e];
    } else {
      dstG = tp_dst[e - E];
      src = NP + tp_src[e - E];
    }
    int b = dstG / BN;
    int dl = dstG - b * BN;
    int pos = base[b] + atomicAdd(&hist[b], 1);
    pk[pos] = ((uint32_t)dl << 20) | (uint32_t)src;
  }
}

// ---------------- bucketed aggregation: agg[n] = bf16(mean src rows) --------
// one block per bucket; LDS fp32 accumulator (stride 68 spreads ds banks);
// 16 lanes per edge, 4 dims per lane.
template <typename T>
__global__ __launch_bounds__(256) void bucket_agg_kernel(
    const int* __restrict__ bucketStart, const int* __restrict__ bucketCount,
    const uint32_t* __restrict__ pk,
    const T* __restrict__ basePl, const T* __restrict__ baseTr,
    uint16_t* __restrict__ agg, int N, int NP) {
  __shared__ float acc[BN * 68];
  __shared__ int cnt[BN];
  int t = threadIdx.x;
  int b = blockIdx.x;
  for (int i = t; i < BN * 68; i += 256) acc[i] = 0.f;
  for (int i = t; i < BN; i += 256) cnt[i] = 0;
  __syncthreads();

  int beg = bucketStart[b];
  int num = bucketCount[b];
  int wave = t >> 6, lane = t & 63;
  int eSub = lane >> 4;   // which of 4 edges in this wave-iteration
  int c = lane & 15;      // dim quad
  int nodeB = b * BN;

  for (int g = wave * 4; g < num; g += 16) {
    int eIdx = g + eSub;
    if (eIdx < num) {
      uint32_t v = pk[beg + eIdx];
      int dl = (int)(v >> 20);
      int src = (int)(v & 0xFFFFFu);
      const T* bx = (nodeB + dl < NP) ? basePl : baseTr;
      f32x4 val = load4f(bx + (size_t)src * 64 + c * 4);
      float* a = &acc[dl * 68 + c * 4];
      atomicAdd(a + 0, val.x);
      atomicAdd(a + 1, val.y);
      atomicAdd(a + 2, val.z);
      atomicAdd(a + 3, val.w);
      if (c == 0) atomicAdd(&cnt[dl], 1);
    }
  }
  __syncthreads();

  for (int r = wave; r < BN; r += 4) {
    int nodeG = nodeB + r;
    if (nodeG >= N) break;
    int dg = cnt[r];
    float inv = 1.0f / (float)(dg > 1 ? dg : 1);
    agg[(size_t)nodeG * 64 + lane] = f2b(acc[r * 68 + lane] * inv);
  }
}

// ---------------- fused transform: xout = relu(x@Wroot + agg@Wrel + b) ------
template <typename XT>
__global__ __launch_bounds__(256) void transform_kernel(
    const XT* __restrict__ xpl, const XT* __restrict__ xtr,
    const uint16_t* __restrict__ agg,
    const float* __restrict__ Wroot,
    const float* __restrict__ WrelP, const float* __restrict__ WrelT,
    const float* __restrict__ biasrow,
    uint16_t* __restrict__ xout, int NP, int NT, int BP) {
  int wave = threadIdx.x >> 6;
  int lane = threadIdx.x & 63;
  int m = lane & 15, q = lane >> 4;

  int wl, nw, ntiles, nodeBase;
  const XT* xbase;
  const float* Wrel;
  if ((int)blockIdx.x < BP) {
    wl = blockIdx.x * 4 + wave; nw = BP * 4; ntiles = NP / 16;
    xbase = xpl; Wrel = WrelP; nodeBase = 0;
  } else {
    wl = (blockIdx.x - BP) * 4 + wave; nw = (gridDim.x - BP) * 4; ntiles = NT / 16;
    xbase = xtr; Wrel = WrelT; nodeBase = NP;
  }

  // B fragments: B[k][n], lane n=16*ct+m, elems k=32*kc+8*q+i
  bf16x8 br[2][4], bl[2][4];
  for (int kc = 0; kc < 2; ++kc)
    for (int ct = 0; ct < 4; ++ct) {
      int n = 16 * ct + m;
      int k0 = 32 * kc + 8 * q;
      bf16x8 t0, t1;
      for (int i = 0; i < 8; ++i) {
        t0[i] = (short)f2b(Wroot[(size_t)(k0 + i) * 64 + n]);
        t1[i] = (short)f2b(Wrel[(size_t)(k0 + i) * 64 + n]);
      }
      br[kc][ct] = t0;
      bl[kc][ct] = t1;
    }
  float bv[4];
  for (int ct = 0; ct < 4; ++ct) bv[ct] = biasrow[16 * ct + m];

  for (int t = wl; t < ntiles; t += nw) {
    int rowLocal = t * 16 + m;  // A row: m = lane&15
    int nodeG = nodeBase + rowLocal;
    const XT* xrow = xbase + (size_t)rowLocal * 64;
    bf16x8 ax0 = load8b(xrow + 8 * q);
    bf16x8 ax1 = load8b(xrow + 32 + 8 * q);

    const uint16_t* arow = agg + (size_t)nodeG * 64;
    bf16x8 aa0 = *(const bf16x8*)(arow + 8 * q);
    bf16x8 aa1 = *(const bf16x8*)(arow + 32 + 8 * q);

    f32x4 acc[4];
#pragma unroll
    for (int ct = 0; ct < 4; ++ct) acc[ct] = (f32x4){bv[ct], bv[ct], bv[ct], bv[ct]};
#pragma unroll
    for (int ct = 0; ct < 4; ++ct) {
      acc[ct] = __builtin_amdgcn_mfma_f32_16x16x32_bf16(ax0, br[0][ct], acc[ct], 0, 0, 0);
      acc[ct] = __builtin_amdgcn_mfma_f32_16x16x32_bf16(ax1, br[1][ct], acc[ct], 0, 0, 0);
      acc[ct] = __builtin_amdgcn_mfma_f32_16x16x32_bf16(aa0, bl[0][ct], acc[ct], 0, 0, 0);
      acc[ct] = __builtin_amdgcn_mfma_f32_16x16x32_bf16(aa1, bl[1][ct], acc[ct], 0, 0, 0);
    }
    // D: row = 4*q + r, col = 16*ct + m
    int nodeRow0 = nodeBase + t * 16;
#pragma unroll
    for (int ct = 0; ct < 4; ++ct)
#pragma unroll
      for (int r = 0; r < 4; ++r) {
        float v = acc[ct][r];
        v = v > 0.0f ? v : 0.0f;
        xout[(size_t)(nodeRow0 + 4 * q + r) * 64 + 16 * ct + m] = f2b(v);
      }
  }
}

// ---------------- link scores: (1/9) * dot(sum_p, sum_t) --------------------
__global__ void score_kernel(const int* __restrict__ ell_pl,
                             const int* __restrict__ ell_tr,
                             const float* __restrict__ emb_pl,
                             const float* __restrict__ emb_tr,
                             const uint16_t* __restrict__ x1,
                             const uint16_t* __restrict__ x2,
                             float* __restrict__ out, int EP, int NP) {
  long g = (long)blockIdx.x * blockDim.x + threadIdx.x;
  long pair = g >> 4;
  int c = (int)(g & 15);
  if (pair >= EP) return;
  int p = ell_pl[pair];
  int t = ell_tr[pair];
  int d0 = c * 4;

  size_t pg = (size_t)p * 64 + d0;
  f32x4 sp = load4f(emb_pl + pg);
  f32x4 a = load4f(x1 + pg);
  f32x4 b = load4f(x2 + pg);
  sp.x += a.x + b.x; sp.y += a.y + b.y; sp.z += a.z + b.z; sp.w += a.w + b.w;

  size_t tl = (size_t)t * 64 + d0;
  size_t tg = (size_t)(NP + t) * 64 + d0;
  f32x4 st = load4f(emb_tr + tl);
  a = load4f(x1 + tg);
  b = load4f(x2 + tg);
  st.x += a.x + b.x; st.y += a.y + b.y; st.z += a.z + b.z; st.w += a.w + b.w;

  float partial = sp.x * st.x + sp.y * st.y + sp.z * st.z + sp.w * st.w;
  partial += __shfl_xor(partial, 1);
  partial += __shfl_xor(partial, 2);
  partial += __shfl_xor(partial, 4);
  partial += __shfl_xor(partial, 8);
  if (c == 0) out[pair] = partial * (1.0f / 9.0f);
}

extern "C" void kernel_launch(void* const* d_in, const int* in_sizes, int n_in,
                              void* d_out, int out_size, void* d_ws, size_t ws_size,
                              hipStream_t stream) {
  const float* emb_pl = (const float*)d_in[0];
  const float* emb_tr = (const float*)d_in[1];
  const float* W_rel = (const float*)d_in[2];   // [L,2,64,64] f32
  const float* W_root = (const float*)d_in[3];  // [L,64,64] f32
  const float* bias = (const float*)d_in[4];    // [L,64] f32
  const int* pt_src = (const int*)d_in[7];
  const int* pt_dst = (const int*)d_in[8];
  const int* tp_src = (const int*)d_in[9];
  const int* tp_dst = (const int*)d_in[10];
  const int* ell_pl = (const int*)d_in[11];
  const int* ell_tr = (const int*)d_in[12];
  float* out = (float*)d_out;

  const int NP = in_sizes[5];
  const int NT = in_sizes[6];
  const int E = in_sizes[7];
  const int EP = in_sizes[11];
  const int N = NP + NT;
  const long TE = 2L * E;
  const int NB = (N + BN - 1) / BN;

  char* ws = (char*)d_ws;
  size_t off = 0;
  uint16_t* agg = (uint16_t*)(ws + off); off += (size_t)N * 64 * 2;   // bf16
  uint16_t* x1  = (uint16_t*)(ws + off); off += (size_t)N * 64 * 2;   // bf16
  uint16_t* x2  = (uint16_t*)(ws + off); off += (size_t)N * 64 * 2;   // bf16
  uint32_t* pk  = (uint32_t*)(ws + off); off += (size_t)TE * 4;
  int* bucketCount = (int*)(ws + off);   off += (size_t)NB * 4;
  int* bucketStart = (int*)(ws + off);   off += (size_t)NB * 4;
  int* gCursor     = (int*)(ws + off);   off += (size_t)NB * 4;

  const int TB = 256;
  const int PB = 256;                          // partition blocks
  int chunk = (int)((TE + PB - 1) / PB);
  int scoreBlocks = (int)(((long)EP * 16 + TB - 1) / TB);
  const int BP = 256, GT = 1024;               // transform grid split

  // ---- bucket build (once; reused by both layers) ----
  hipMemsetAsync(bucketCount, 0, (size_t)NB * 4, stream);
  bucket_hist_kernel<<<128, TB, NB * 4, stream>>>(pt_dst, tp_dst, bucketCount,
                                                  E, NP, NB);
  bucket_scan_kernel<<<1, 1024, 0, stream>>>(bucketCount, bucketStart, gCursor, NB);
  partition_kernel<<<PB, 512, 2 * NB * 4, stream>>>(
      pt_src, pt_dst, tp_src, tp_dst, gCursor, pk, E, NP, NB, chunk);

  // ---- layer 0 (x = fp32 embeddings) ----
  // dst<NP pulls track rows (src>=NP): base = emb_tr - NP*64; dst>=NP: emb_pl
  const float* basePl0 = emb_tr - (size_t)NP * 64;
  bucket_agg_kernel<float><<<NB, TB, 0, stream>>>(
      bucketStart, bucketCount, pk, basePl0, emb_pl, agg, N, NP);
  transform_kernel<float><<<GT, TB, 0, stream>>>(
      emb_pl, emb_tr, agg, W_root + 0 * 4096, W_rel + 1 * 4096,
      W_rel + 0 * 4096, bias + 0, x1, NP, NT, BP);

  // ---- layer 1 (x = x1, bf16, global src indexing) ----
  bucket_agg_kernel<uint16_t><<<NB, TB, 0, stream>>>(
      bucketStart, bucketCount, pk, x1, x1, agg, N, NP);
  transform_kernel<uint16_t><<<GT, TB, 0, stream>>>(
      x1, x1 + (size_t)NP * 64, agg, W_root + 1 * 4096, W_rel + 3 * 4096,
      W_rel + 2 * 4096, bias + 64, x2, NP, NT, BP);

  // ---- link scores ----
  score_kernel<<<scoreBlocks, TB, 0, stream>>>(ell_pl, ell_tr, emb_pl, emb_tr,
                                               x1, x2, out, EP, NP);
}

// Round 6
// 757.077 us; speedup vs baseline: 4.1307x; 4.1307x over previous
//
#include <hip/hip_runtime.h>
#include <stdint.h>

typedef __attribute__((ext_vector_type(8))) short bf16x8;
typedef __attribute__((ext_vector_type(4))) float f32x4;

#define BN 192  // dst nodes per bucket (fits 256-wide LDS scan)

static __device__ __forceinline__ float b2f_lo(uint32_t w) {
  union { uint32_t u; float f; } c; c.u = w << 16; return c.f;
}
static __device__ __forceinline__ float b2f_hi(uint32_t w) {
  union { uint32_t u; float f; } c; c.u = w & 0xffff0000u; return c.f;
}
static __device__ __forceinline__ uint16_t f2b(float f) {
  union { float f; uint32_t u; } c; c.f = f;
  return (uint16_t)((c.u + 0x7fffu + ((c.u >> 16) & 1u)) >> 16);
}
static __device__ __forceinline__ float belem(const uint16_t* p) {
  union { uint32_t u; float f; } c; c.u = ((uint32_t)(*p)) << 16; return c.f;
}
static __device__ __forceinline__ f32x4 load4f(const float* p) {
  return *(const f32x4*)p;
}
static __device__ __forceinline__ f32x4 load4f(const uint16_t* p) {
  uint2 t = *(const uint2*)p;
  f32x4 r;
  r.x = b2f_lo(t.x); r.y = b2f_hi(t.x);
  r.z = b2f_lo(t.y); r.w = b2f_hi(t.y);
  return r;
}

// ---------------- fp32 -> bf16 embedding conversion (into xb buffer) --------
__global__ __launch_bounds__(256) void convert_kernel(
    const float* __restrict__ emb_pl, const float* __restrict__ emb_tr,
    uint16_t* __restrict__ xb, int NP, int N) {
  long g = (long)blockIdx.x * 256 + threadIdx.x;
  long base8 = g * 8;
  long total = (long)N * 64;
  if (base8 >= total) return;
  long plEnd = (long)NP * 64;  // divisible by 8, no straddle
  const float* src = (base8 < plEnd) ? (emb_pl + base8) : (emb_tr + (base8 - plEnd));
  f32x4 a = *(const f32x4*)src;
  f32x4 b = *(const f32x4*)(src + 4);
  union { uint16_t h[8]; uint2 v[2]; } o;
  o.h[0] = f2b(a.x); o.h[1] = f2b(a.y); o.h[2] = f2b(a.z); o.h[3] = f2b(a.w);
  o.h[4] = f2b(b.x); o.h[5] = f2b(b.y); o.h[6] = f2b(b.z); o.h[7] = f2b(b.w);
  *(uint2*)(xb + base8) = o.v[0];
  *(uint2*)(xb + base8 + 4) = o.v[1];
}

// ---------------- bucket histogram over dst (both relations) ----------------
__global__ __launch_bounds__(256) void bucket_hist_kernel(
    const int* __restrict__ pt_dst, const int* __restrict__ tp_dst,
    int* __restrict__ bucketCount, int E, int NP, int NB) {
  extern __shared__ int hist[];
  int t = threadIdx.x;
  for (int b = t; b < NB; b += 256) hist[b] = 0;
  __syncthreads();
  long total = 2L * E;
  long stride = (long)gridDim.x * 256;
  for (long e = (long)blockIdx.x * 256 + t; e < total; e += stride) {
    int dstG = (e < E) ? (NP + pt_dst[e]) : tp_dst[e - E];
    atomicAdd(&hist[dstG / BN], 1);
  }
  __syncthreads();
  for (int b = t; b < NB; b += 256) {
    int h = hist[b];
    if (h > 0) atomicAdd(&bucketCount[b], h);
  }
}

// ---------------- exclusive scan of bucket counts (1 block) -----------------
__global__ __launch_bounds__(1024) void bucket_scan_kernel(
    const int* __restrict__ bucketCount, int* __restrict__ bucketStart,
    int* __restrict__ gCursor, int NB) {
  __shared__ int s[1024];
  int t = threadIdx.x;
  int K = (NB + 1023) >> 10;
  int b0 = t * K;
  int local = 0;
  for (int j = 0; j < K; ++j) {
    int b = b0 + j;
    if (b < NB) local += bucketCount[b];
  }
  int acc = local;
  s[t] = local;
  __syncthreads();
  for (int off = 1; off < 1024; off <<= 1) {
    int u = (t >= off) ? s[t - off] : 0;
    __syncthreads();
    acc += u;
    s[t] = acc;
    __syncthreads();
  }
  int run = acc - local;  // exclusive prefix of this thread's chunk
  for (int j = 0; j < K; ++j) {
    int b = b0 + j;
    if (b < NB) {
      bucketStart[b] = run;
      gCursor[b] = run;
      run += bucketCount[b];
    }
  }
}

// ---------------- partition: pk[slot] = (dl<<20)|srcGlobal ------------------
// chunked two-phase multi-split: local hist -> reserve ranges -> write.
__global__ __launch_bounds__(512) void partition_kernel(
    const int* __restrict__ pt_src, const int* __restrict__ pt_dst,
    const int* __restrict__ tp_src, const int* __restrict__ tp_dst,
    int* __restrict__ gCursor, uint32_t* __restrict__ pk,
    int E, int NP, int NB, int chunk) {
  extern __shared__ int lds[];
  int* hist = lds;        // [NB]
  int* base = lds + NB;   // [NB]
  int t = threadIdx.x;
  long e0 = (long)blockIdx.x * chunk;
  long e1 = e0 + chunk;
  long total = 2L * E;
  if (e1 > total) e1 = total;
  for (int b = t; b < NB; b += 512) hist[b] = 0;
  __syncthreads();
  for (long e = e0 + t; e < e1; e += 512) {
    int dstG = (e < E) ? (NP + pt_dst[e]) : tp_dst[e - E];
    atomicAdd(&hist[dstG / BN], 1);
  }
  __syncthreads();
  for (int b = t; b < NB; b += 512) {
    int h = hist[b];
    base[b] = (h > 0) ? atomicAdd(&gCursor[b], h) : 0;
    hist[b] = 0;  // reuse as local cursor
  }
  __syncthreads();
  for (long e = e0 + t; e < e1; e += 512) {
    int dstG, src;
    if (e < E) {
      dstG = NP + pt_dst[e];
      src = pt_src[e];
    } else {
      dstG = tp_dst[e - E];
      src = NP + tp_src[e - E];
    }
    int b = dstG / BN;
    int dl = dstG - b * BN;
    int pos = base[b] + atomicAdd(&hist[b], 1);
    pk[pos] = ((uint32_t)dl << 20) | (uint32_t)src;
  }
}

// ---------------- per-bucket counting sort -> node-grouped CSR --------------
// writes confined to this bucket's ~15 KB col range => L2-friendly.
__global__ __launch_bounds__(256) void local_csr_kernel(
    const int* __restrict__ bucketStart, const int* __restrict__ bucketCount,
    const uint32_t* __restrict__ pk, int* __restrict__ rowptr,
    int* __restrict__ col, int N, int TEtotal) {
  __shared__ int hist[256];
  __shared__ int cur[256];
  int t = threadIdx.x;
  int b = blockIdx.x;
  hist[t] = 0;
  __syncthreads();
  int beg = bucketStart[b], num = bucketCount[b];
  for (int i = t; i < num; i += 256)
    atomicAdd(&hist[pk[beg + i] >> 20], 1);
  __syncthreads();
  int v = hist[t];
  int acc = v;
  cur[t] = v;
  __syncthreads();
  for (int off = 1; off < 256; off <<= 1) {
    int u = (t >= off) ? cur[t - off] : 0;
    __syncthreads();
    acc += u;
    cur[t] = acc;
    __syncthreads();
  }
  int excl = acc - v;
  int node = b * BN + t;
  if (t < BN && node < N) rowptr[node] = beg + excl;
  cur[t] = excl;
  __syncthreads();
  for (int i = t; i < num; i += 256) {
    uint32_t w = pk[beg + i];
    int dl = (int)(w >> 20);
    int pos = atomicAdd(&cur[dl], 1);
    col[beg + pos] = (int)(w & 0xFFFFFu);
  }
  if (b == 0 && t == 0) rowptr[N] = TEtotal;
}

// ---------------- pull aggregation: agg[n] = bf16(mean of src rows) ---------
// one wave per node, lane = dim; register accumulate; 8 rows in flight.
__global__ __launch_bounds__(256) void pull_kernel(
    const int* __restrict__ rowptr, const int* __restrict__ col,
    const uint16_t* __restrict__ base, uint16_t* __restrict__ agg, int N) {
  int node = blockIdx.x * 4 + (threadIdx.x >> 6);
  int lane = threadIdx.x & 63;
  if (node >= N) return;
  int beg = rowptr[node], end = rowptr[node + 1];
  float s = 0.f;
  int i = beg;
  for (; i + 8 <= end; i += 8) {
    int c0 = col[i], c1 = col[i + 1], c2 = col[i + 2], c3 = col[i + 3];
    int c4 = col[i + 4], c5 = col[i + 5], c6 = col[i + 6], c7 = col[i + 7];
    float v0 = belem(base + (size_t)c0 * 64 + lane);
    float v1 = belem(base + (size_t)c1 * 64 + lane);
    float v2 = belem(base + (size_t)c2 * 64 + lane);
    float v3 = belem(base + (size_t)c3 * 64 + lane);
    float v4 = belem(base + (size_t)c4 * 64 + lane);
    float v5 = belem(base + (size_t)c5 * 64 + lane);
    float v6 = belem(base + (size_t)c6 * 64 + lane);
    float v7 = belem(base + (size_t)c7 * 64 + lane);
    s += ((v0 + v1) + (v2 + v3)) + ((v4 + v5) + (v6 + v7));
  }
  for (; i + 4 <= end; i += 4) {
    int c0 = col[i], c1 = col[i + 1], c2 = col[i + 2], c3 = col[i + 3];
    float v0 = belem(base + (size_t)c0 * 64 + lane);
    float v1 = belem(base + (size_t)c1 * 64 + lane);
    float v2 = belem(base + (size_t)c2 * 64 + lane);
    float v3 = belem(base + (size_t)c3 * 64 + lane);
    s += (v0 + v1) + (v2 + v3);
  }
  for (; i < end; ++i) s += belem(base + (size_t)col[i] * 64 + lane);
  int deg = end - beg;
  float inv = 1.0f / (float)(deg > 1 ? deg : 1);
  agg[(size_t)node * 64 + lane] = f2b(s * inv);
}

// ---------------- fused transform: xout = relu(x@Wroot + agg@Wrel + b) ------
__global__ __launch_bounds__(256) void transform_kernel(
    const uint16_t* __restrict__ xpl, const uint16_t* __restrict__ xtr,
    const uint16_t* __restrict__ agg,
    const float* __restrict__ Wroot,
    const float* __restrict__ WrelP, const float* __restrict__ WrelT,
    const float* __restrict__ biasrow,
    uint16_t* __restrict__ xout, int NP, int NT, int BP) {
  int wave = threadIdx.x >> 6;
  int lane = threadIdx.x & 63;
  int m = lane & 15, q = lane >> 4;

  int wl, nw, ntiles, nodeBase;
  const uint16_t* xbase;
  const float* Wrel;
  if ((int)blockIdx.x < BP) {
    wl = blockIdx.x * 4 + wave; nw = BP * 4; ntiles = NP / 16;
    xbase = xpl; Wrel = WrelP; nodeBase = 0;
  } else {
    wl = (blockIdx.x - BP) * 4 + wave; nw = (gridDim.x - BP) * 4; ntiles = NT / 16;
    xbase = xtr; Wrel = WrelT; nodeBase = NP;
  }

  // B fragments: B[k][n], lane n=16*ct+m, elems k=32*kc+8*q+i
  bf16x8 br[2][4], bl[2][4];
  for (int kc = 0; kc < 2; ++kc)
    for (int ct = 0; ct < 4; ++ct) {
      int n = 16 * ct + m;
      int k0 = 32 * kc + 8 * q;
      bf16x8 t0, t1;
      for (int i = 0; i < 8; ++i) {
        t0[i] = (short)f2b(Wroot[(size_t)(k0 + i) * 64 + n]);
        t1[i] = (short)f2b(Wrel[(size_t)(k0 + i) * 64 + n]);
      }
      br[kc][ct] = t0;
      bl[kc][ct] = t1;
    }
  float bv[4];
  for (int ct = 0; ct < 4; ++ct) bv[ct] = biasrow[16 * ct + m];

  for (int t = wl; t < ntiles; t += nw) {
    int rowLocal = t * 16 + m;  // A row: m = lane&15
    int nodeG = nodeBase + rowLocal;
    const uint16_t* xrow = xbase + (size_t)rowLocal * 64;
    bf16x8 ax0 = *(const bf16x8*)(xrow + 8 * q);
    bf16x8 ax1 = *(const bf16x8*)(xrow + 32 + 8 * q);

    const uint16_t* arow = agg + (size_t)nodeG * 64;
    bf16x8 aa0 = *(const bf16x8*)(arow + 8 * q);
    bf16x8 aa1 = *(const bf16x8*)(arow + 32 + 8 * q);

    f32x4 acc[4];
#pragma unroll
    for (int ct = 0; ct < 4; ++ct) acc[ct] = (f32x4){bv[ct], bv[ct], bv[ct], bv[ct]};
#pragma unroll
    for (int ct = 0; ct < 4; ++ct) {
      acc[ct] = __builtin_amdgcn_mfma_f32_16x16x32_bf16(ax0, br[0][ct], acc[ct], 0, 0, 0);
      acc[ct] = __builtin_amdgcn_mfma_f32_16x16x32_bf16(ax1, br[1][ct], acc[ct], 0, 0, 0);
      acc[ct] = __builtin_amdgcn_mfma_f32_16x16x32_bf16(aa0, bl[0][ct], acc[ct], 0, 0, 0);
      acc[ct] = __builtin_amdgcn_mfma_f32_16x16x32_bf16(aa1, bl[1][ct], acc[ct], 0, 0, 0);
    }
    // D: row = 4*q + r, col = 16*ct + m
    int nodeRow0 = nodeBase + t * 16;
#pragma unroll
    for (int ct = 0; ct < 4; ++ct)
#pragma unroll
      for (int r = 0; r < 4; ++r) {
        float v = acc[ct][r];
        v = v > 0.0f ? v : 0.0f;
        xout[(size_t)(nodeRow0 + 4 * q + r) * 64 + 16 * ct + m] = f2b(v);
      }
  }
}

// ---------------- link scores: (1/9) * dot(sum_p, sum_t) --------------------
__global__ void score_kernel(const int* __restrict__ ell_pl,
                             const int* __restrict__ ell_tr,
                             const float* __restrict__ emb_pl,
                             const float* __restrict__ emb_tr,
                             const uint16_t* __restrict__ x1,
                             const uint16_t* __restrict__ x2,
                             float* __restrict__ out, int EP, int NP) {
  long g = (long)blockIdx.x * blockDim.x + threadIdx.x;
  long pair = g >> 4;
  int c = (int)(g & 15);
  if (pair >= EP) return;
  int p = ell_pl[pair];
  int t = ell_tr[pair];
  int d0 = c * 4;

  size_t pg = (size_t)p * 64 + d0;
  f32x4 sp = load4f(emb_pl + pg);
  f32x4 a = load4f(x1 + pg);
  f32x4 b = load4f(x2 + pg);
  sp.x += a.x + b.x; sp.y += a.y + b.y; sp.z += a.z + b.z; sp.w += a.w + b.w;

  size_t tl = (size_t)t * 64 + d0;
  size_t tg = (size_t)(NP + t) * 64 + d0;
  f32x4 st = load4f(emb_tr + tl);
  a = load4f(x1 + tg);
  b = load4f(x2 + tg);
  st.x += a.x + b.x; st.y += a.y + b.y; st.z += a.z + b.z; st.w += a.w + b.w;

  float partial = sp.x * st.x + sp.y * st.y + sp.z * st.z + sp.w * st.w;
  partial += __shfl_xor(partial, 1);
  partial += __shfl_xor(partial, 2);
  partial += __shfl_xor(partial, 4);
  partial += __shfl_xor(partial, 8);
  if (c == 0) out[pair] = partial * (1.0f / 9.0f);
}

extern "C" void kernel_launch(void* const* d_in, const int* in_sizes, int n_in,
                              void* d_out, int out_size, void* d_ws, size_t ws_size,
                              hipStream_t stream) {
  const float* emb_pl = (const float*)d_in[0];
  const float* emb_tr = (const float*)d_in[1];
  const float* W_rel = (const float*)d_in[2];   // [L,2,64,64] f32
  const float* W_root = (const float*)d_in[3];  // [L,64,64] f32
  const float* bias = (const float*)d_in[4];    // [L,64] f32
  const int* pt_src = (const int*)d_in[7];
  const int* pt_dst = (const int*)d_in[8];
  const int* tp_src = (const int*)d_in[9];
  const int* tp_dst = (const int*)d_in[10];
  const int* ell_pl = (const int*)d_in[11];
  const int* ell_tr = (const int*)d_in[12];
  float* out = (float*)d_out;

  const int NP = in_sizes[5];
  const int NT = in_sizes[6];
  const int E = in_sizes[7];
  const int EP = in_sizes[11];
  const int N = NP + NT;
  const long TE = 2L * E;
  const int NB = (N + BN - 1) / BN;

  char* ws = (char*)d_ws;
  size_t off = 0;
  uint16_t* agg = (uint16_t*)(ws + off); off += (size_t)N * 64 * 2;   // bf16
  uint16_t* x1  = (uint16_t*)(ws + off); off += (size_t)N * 64 * 2;   // bf16
  uint16_t* x2  = (uint16_t*)(ws + off); off += (size_t)N * 64 * 2;   // bf16 (xb0 early)
  uint32_t* pk  = (uint32_t*)(ws + off); off += (size_t)TE * 4;
  int* col      = (int*)(ws + off);      off += (size_t)TE * 4;
  int* rowptr   = (int*)(ws + off);      off += (size_t)(N + 1) * 4;
  int* bucketCount = (int*)(ws + off);   off += (size_t)NB * 4;
  int* bucketStart = (int*)(ws + off);   off += (size_t)NB * 4;
  int* gCursor     = (int*)(ws + off);   off += (size_t)NB * 4;

  uint16_t* xb0 = x2;  // x2 slot doubles as bf16 embedding copy until transform1

  const int TB = 256;
  const int PB = 256;  // partition blocks
  int chunk = (int)((TE + PB - 1) / PB);
  long cvt = ((long)N * 64 / 8 + TB - 1) / TB;
  int pullBlocks = (N + 3) / 4;
  int scoreBlocks = (int)(((long)EP * 16 + TB - 1) / TB);
  const int BP = 256, GT = 1024;  // transform grid split

  // ---- bf16 embedding copy (used by pull0 + transform0) ----
  convert_kernel<<<(int)cvt, TB, 0, stream>>>(emb_pl, emb_tr, xb0, NP, N);

  // ---- bucket build (once; reused by both layers) ----
  hipMemsetAsync(bucketCount, 0, (size_t)NB * 4, stream);
  bucket_hist_kernel<<<128, TB, NB * 4, stream>>>(pt_dst, tp_dst, bucketCount,
                                                  E, NP, NB);
  bucket_scan_kernel<<<1, 1024, 0, stream>>>(bucketCount, bucketStart, gCursor, NB);
  partition_kernel<<<PB, 512, 2 * NB * 4, stream>>>(
      pt_src, pt_dst, tp_src, tp_dst, gCursor, pk, E, NP, NB, chunk);
  local_csr_kernel<<<NB, TB, 0, stream>>>(bucketStart, bucketCount, pk,
                                          rowptr, col, N, (int)TE);

  // ---- layer 0 (x = bf16 embedding copy, global indexing) ----
  pull_kernel<<<pullBlocks, TB, 0, stream>>>(rowptr, col, xb0, agg, N);
  transform_kernel<<<GT, TB, 0, stream>>>(
      xb0, xb0 + (size_t)NP * 64, agg, W_root + 0 * 4096, W_rel + 1 * 4096,
      W_rel + 0 * 4096, bias + 0, x1, NP, NT, BP);

  // ---- layer 1 (x = x1) ----
  pull_kernel<<<pullBlocks, TB, 0, stream>>>(rowptr, col, x1, agg, N);
  transform_kernel<<<GT, TB, 0, stream>>>(
      x1, x1 + (size_t)NP * 64, agg, W_root + 1 * 4096, W_rel + 3 * 4096,
      W_rel + 2 * 4096, bias + 64, x2, NP, NT, BP);

  // ---- link scores ----
  score_kernel<<<scoreBlocks, TB, 0, stream>>>(ell_pl, ell_tr, emb_pl, emb_tr,
                                               x1, x2, out, EP, NP);
}

// Round 7
// 621.262 us; speedup vs baseline: 5.0338x; 1.2186x over previous
//
#include <hip/hip_runtime.h>
#include <stdint.h>

typedef __attribute__((ext_vector_type(8))) short bf16x8;
typedef __attribute__((ext_vector_type(4))) float f32x4;

#define BN 192  // dst nodes per bucket (fits 256-wide LDS scan)

static __device__ __forceinline__ float b2f_lo(uint32_t w) {
  union { uint32_t u; float f; } c; c.u = w << 16; return c.f;
}
static __device__ __forceinline__ float b2f_hi(uint32_t w) {
  union { uint32_t u; float f; } c; c.u = w & 0xffff0000u; return c.f;
}
static __device__ __forceinline__ uint16_t f2b(float f) {
  union { float f; uint32_t u; } c; c.f = f;
  return (uint16_t)((c.u + 0x7fffu + ((c.u >> 16) & 1u)) >> 16);
}
static __device__ __forceinline__ f32x4 unpack4(uint2 t) {
  f32x4 r;
  r.x = b2f_lo(t.x); r.y = b2f_hi(t.x);
  r.z = b2f_lo(t.y); r.w = b2f_hi(t.y);
  return r;
}

// ---------------- fp32 -> bf16 embedding conversion (into xb buffer) --------
__global__ __launch_bounds__(256) void convert_kernel(
    const float* __restrict__ emb_pl, const float* __restrict__ emb_tr,
    uint16_t* __restrict__ xb, int NP, int N) {
  long g = (long)blockIdx.x * 256 + threadIdx.x;
  long base8 = g * 8;
  long total = (long)N * 64;
  if (base8 >= total) return;
  long plEnd = (long)NP * 64;  // divisible by 8, no straddle
  const float* src = (base8 < plEnd) ? (emb_pl + base8) : (emb_tr + (base8 - plEnd));
  f32x4 a = *(const f32x4*)src;
  f32x4 b = *(const f32x4*)(src + 4);
  union { uint16_t h[8]; uint2 v[2]; } o;
  o.h[0] = f2b(a.x); o.h[1] = f2b(a.y); o.h[2] = f2b(a.z); o.h[3] = f2b(a.w);
  o.h[4] = f2b(b.x); o.h[5] = f2b(b.y); o.h[6] = f2b(b.z); o.h[7] = f2b(b.w);
  *(uint2*)(xb + base8) = o.v[0];
  *(uint2*)(xb + base8 + 4) = o.v[1];
}

// ---------------- bucket histogram over dst (both relations) ----------------
__global__ __launch_bounds__(256) void bucket_hist_kernel(
    const int* __restrict__ pt_dst, const int* __restrict__ tp_dst,
    int* __restrict__ bucketCount, int E, int NP, int NB) {
  extern __shared__ int hist[];
  int t = threadIdx.x;
  for (int b = t; b < NB; b += 256) hist[b] = 0;
  __syncthreads();
  long total = 2L * E;
  long stride = (long)gridDim.x * 256;
  for (long e = (long)blockIdx.x * 256 + t; e < total; e += stride) {
    int dstG = (e < E) ? (NP + pt_dst[e]) : tp_dst[e - E];
    atomicAdd(&hist[dstG / BN], 1);
  }
  __syncthreads();
  for (int b = t; b < NB; b += 256) {
    int h = hist[b];
    if (h > 0) atomicAdd(&bucketCount[b], h);
  }
}

// ---------------- exclusive scan of bucket counts (1 block) -----------------
__global__ __launch_bounds__(1024) void bucket_scan_kernel(
    const int* __restrict__ bucketCount, int* __restrict__ bucketStart,
    int* __restrict__ gCursor, int NB) {
  __shared__ int s[1024];
  int t = threadIdx.x;
  int K = (NB + 1023) >> 10;
  int b0 = t * K;
  int local = 0;
  for (int j = 0; j < K; ++j) {
    int b = b0 + j;
    if (b < NB) local += bucketCount[b];
  }
  int acc = local;
  s[t] = local;
  __syncthreads();
  for (int off = 1; off < 1024; off <<= 1) {
    int u = (t >= off) ? s[t - off] : 0;
    __syncthreads();
    acc += u;
    s[t] = acc;
    __syncthreads();
  }
  int run = acc - local;  // exclusive prefix of this thread's chunk
  for (int j = 0; j < K; ++j) {
    int b = b0 + j;
    if (b < NB) {
      bucketStart[b] = run;
      gCursor[b] = run;
      run += bucketCount[b];
    }
  }
}

// ---------------- partition: pk[slot] = (dl<<20)|srcGlobal ------------------
__global__ __launch_bounds__(512) void partition_kernel(
    const int* __restrict__ pt_src, const int* __restrict__ pt_dst,
    const int* __restrict__ tp_src, const int* __restrict__ tp_dst,
    int* __restrict__ gCursor, uint32_t* __restrict__ pk,
    int E, int NP, int NB, int chunk) {
  extern __shared__ int lds[];
  int* hist = lds;        // [NB]
  int* base = lds + NB;   // [NB]
  int t = threadIdx.x;
  long e0 = (long)blockIdx.x * chunk;
  long e1 = e0 + chunk;
  long total = 2L * E;
  if (e1 > total) e1 = total;
  for (int b = t; b < NB; b += 512) hist[b] = 0;
  __syncthreads();
  for (long e = e0 + t; e < e1; e += 512) {
    int dstG = (e < E) ? (NP + pt_dst[e]) : tp_dst[e - E];
    atomicAdd(&hist[dstG / BN], 1);
  }
  __syncthreads();
  for (int b = t; b < NB; b += 512) {
    int h = hist[b];
    base[b] = (h > 0) ? atomicAdd(&gCursor[b], h) : 0;
    hist[b] = 0;  // reuse as local cursor
  }
  __syncthreads();
  for (long e = e0 + t; e < e1; e += 512) {
    int dstG, src;
    if (e < E) {
      dstG = NP + pt_dst[e];
      src = pt_src[e];
    } else {
      dstG = tp_dst[e - E];
      src = NP + tp_src[e - E];
    }
    int b = dstG / BN;
    int dl = dstG - b * BN;
    int pos = base[b] + atomicAdd(&hist[b], 1);
    pk[pos] = ((uint32_t)dl << 20) | (uint32_t)src;
  }
}

// ---------------- per-bucket counting sort -> node-grouped CSR --------------
__global__ __launch_bounds__(256) void local_csr_kernel(
    const int* __restrict__ bucketStart, const int* __restrict__ bucketCount,
    const uint32_t* __restrict__ pk, int* __restrict__ rowptr,
    int* __restrict__ col, int N, int TEtotal) {
  __shared__ int hist[256];
  __shared__ int cur[256];
  int t = threadIdx.x;
  int b = blockIdx.x;
  hist[t] = 0;
  __syncthreads();
  int beg = bucketStart[b], num = bucketCount[b];
  for (int i = t; i < num; i += 256)
    atomicAdd(&hist[pk[beg + i] >> 20], 1);
  __syncthreads();
  int v = hist[t];
  int acc = v;
  cur[t] = v;
  __syncthreads();
  for (int off = 1; off < 256; off <<= 1) {
    int u = (t >= off) ? cur[t - off] : 0;
    __syncthreads();
    acc += u;
    cur[t] = acc;
    __syncthreads();
  }
  int excl = acc - v;
  int node = b * BN + t;
  if (t < BN && node < N) rowptr[node] = beg + excl;
  cur[t] = excl;
  __syncthreads();
  for (int i = t; i < num; i += 256) {
    uint32_t w = pk[beg + i];
    int dl = (int)(w >> 20);
    int pos = atomicAdd(&cur[dl], 1);
    col[beg + pos] = (int)(w & 0xFFFFFu);
  }
  if (b == 0 && t == 0) rowptr[N] = TEtotal;
}

// ---------------- pull aggregation: agg[n] = bf16(mean of src rows) ---------
// 16 lanes per node (4 nodes/wave), lane handles 4 dims via uint2 loads.
__global__ __launch_bounds__(256) void pull_kernel(
    const int* __restrict__ rowptr, const int* __restrict__ col,
    const uint16_t* __restrict__ base, uint16_t* __restrict__ agg, int N) {
  int node = blockIdx.x * 16 + (threadIdx.x >> 4);
  int c = threadIdx.x & 15;  // dims 4c..4c+3
  if (node >= N) return;
  int beg = rowptr[node], end = rowptr[node + 1];
  float s0 = 0.f, s1 = 0.f, s2 = 0.f, s3 = 0.f;
  int i = beg;
  for (; i + 4 <= end; i += 4) {
    int c0 = col[i], c1 = col[i + 1], c2 = col[i + 2], c3 = col[i + 3];
    uint2 v0 = *(const uint2*)(base + (size_t)c0 * 64 + c * 4);
    uint2 v1 = *(const uint2*)(base + (size_t)c1 * 64 + c * 4);
    uint2 v2 = *(const uint2*)(base + (size_t)c2 * 64 + c * 4);
    uint2 v3 = *(const uint2*)(base + (size_t)c3 * 64 + c * 4);
    f32x4 f0 = unpack4(v0), f1 = unpack4(v1), f2 = unpack4(v2), f3 = unpack4(v3);
    s0 += (f0.x + f1.x) + (f2.x + f3.x);
    s1 += (f0.y + f1.y) + (f2.y + f3.y);
    s2 += (f0.z + f1.z) + (f2.z + f3.z);
    s3 += (f0.w + f1.w) + (f2.w + f3.w);
  }
  for (; i < end; ++i) {
    uint2 v = *(const uint2*)(base + (size_t)col[i] * 64 + c * 4);
    f32x4 f = unpack4(v);
    s0 += f.x; s1 += f.y; s2 += f.z; s3 += f.w;
  }
  int deg = end - beg;
  float inv = 1.0f / (float)(deg > 1 ? deg : 1);
  union { uint16_t h[4]; uint2 v; } o;
  o.h[0] = f2b(s0 * inv); o.h[1] = f2b(s1 * inv);
  o.h[2] = f2b(s2 * inv); o.h[3] = f2b(s3 * inv);
  *(uint2*)(agg + (size_t)node * 64 + c * 4) = o.v;
}

// ---------------- fused transform: xout = relu(x@Wroot + agg@Wrel + b) ------
__global__ __launch_bounds__(256) void transform_kernel(
    const uint16_t* __restrict__ xpl, const uint16_t* __restrict__ xtr,
    const uint16_t* __restrict__ agg,
    const float* __restrict__ Wroot,
    const float* __restrict__ WrelP, const float* __restrict__ WrelT,
    const float* __restrict__ biasrow,
    uint16_t* __restrict__ xout, int NP, int NT, int BP) {
  int wave = threadIdx.x >> 6;
  int lane = threadIdx.x & 63;
  int m = lane & 15, q = lane >> 4;

  int wl, nw, ntiles, nodeBase;
  const uint16_t* xbase;
  const float* Wrel;
  if ((int)blockIdx.x < BP) {
    wl = blockIdx.x * 4 + wave; nw = BP * 4; ntiles = NP / 16;
    xbase = xpl; Wrel = WrelP; nodeBase = 0;
  } else {
    wl = (blockIdx.x - BP) * 4 + wave; nw = (gridDim.x - BP) * 4; ntiles = NT / 16;
    xbase = xtr; Wrel = WrelT; nodeBase = NP;
  }

  // B fragments: B[k][n], lane n=16*ct+m, elems k=32*kc+8*q+i
  bf16x8 br[2][4], bl[2][4];
  for (int kc = 0; kc < 2; ++kc)
    for (int ct = 0; ct < 4; ++ct) {
      int n = 16 * ct + m;
      int k0 = 32 * kc + 8 * q;
      bf16x8 t0, t1;
      for (int i = 0; i < 8; ++i) {
        t0[i] = (short)f2b(Wroot[(size_t)(k0 + i) * 64 + n]);
        t1[i] = (short)f2b(Wrel[(size_t)(k0 + i) * 64 + n]);
      }
      br[kc][ct] = t0;
      bl[kc][ct] = t1;
    }
  float bv[4];
  for (int ct = 0; ct < 4; ++ct) bv[ct] = biasrow[16 * ct + m];

  for (int t = wl; t < ntiles; t += nw) {
    int rowLocal = t * 16 + m;  // A row: m = lane&15
    int nodeG = nodeBase + rowLocal;
    const uint16_t* xrow = xbase + (size_t)rowLocal * 64;
    bf16x8 ax0 = *(const bf16x8*)(xrow + 8 * q);
    bf16x8 ax1 = *(const bf16x8*)(xrow + 32 + 8 * q);

    const uint16_t* arow = agg + (size_t)nodeG * 64;
    bf16x8 aa0 = *(const bf16x8*)(arow + 8 * q);
    bf16x8 aa1 = *(const bf16x8*)(arow + 32 + 8 * q);

    f32x4 acc[4];
#pragma unroll
    for (int ct = 0; ct < 4; ++ct) acc[ct] = (f32x4){bv[ct], bv[ct], bv[ct], bv[ct]};
#pragma unroll
    for (int ct = 0; ct < 4; ++ct) {
      acc[ct] = __builtin_amdgcn_mfma_f32_16x16x32_bf16(ax0, br[0][ct], acc[ct], 0, 0, 0);
      acc[ct] = __builtin_amdgcn_mfma_f32_16x16x32_bf16(ax1, br[1][ct], acc[ct], 0, 0, 0);
      acc[ct] = __builtin_amdgcn_mfma_f32_16x16x32_bf16(aa0, bl[0][ct], acc[ct], 0, 0, 0);
      acc[ct] = __builtin_amdgcn_mfma_f32_16x16x32_bf16(aa1, bl[1][ct], acc[ct], 0, 0, 0);
    }
    // D: row = 4*q + r, col = 16*ct + m
    int nodeRow0 = nodeBase + t * 16;
#pragma unroll
    for (int ct = 0; ct < 4; ++ct)
#pragma unroll
      for (int r = 0; r < 4; ++r) {
        float v = acc[ct][r];
        v = v > 0.0f ? v : 0.0f;
        xout[(size_t)(nodeRow0 + 4 * q + r) * 64 + 16 * ct + m] = f2b(v);
      }
  }
}

// ---------------- node sums: S = bf16(emb + x1 + x2) ------------------------
__global__ __launch_bounds__(256) void sum_kernel(
    const float* __restrict__ emb_pl, const float* __restrict__ emb_tr,
    const uint16_t* __restrict__ x1, const uint16_t* __restrict__ x2,
    uint16_t* __restrict__ S, int NP, int N) {
  long g = (long)blockIdx.x * 256 + threadIdx.x;
  long b8 = g * 8;
  long total = (long)N * 64;
  if (b8 >= total) return;
  long plEnd = (long)NP * 64;
  const float* e = (b8 < plEnd) ? (emb_pl + b8) : (emb_tr + (b8 - plEnd));
  f32x4 ea = *(const f32x4*)e;
  f32x4 eb = *(const f32x4*)(e + 4);
  uint2 x1a = *(const uint2*)(x1 + b8), x1b = *(const uint2*)(x1 + b8 + 4);
  uint2 x2a = *(const uint2*)(x2 + b8), x2b = *(const uint2*)(x2 + b8 + 4);
  f32x4 fa1 = unpack4(x1a), fb1 = unpack4(x1b);
  f32x4 fa2 = unpack4(x2a), fb2 = unpack4(x2b);
  union { uint16_t h[8]; uint4 v; } o;
  o.h[0] = f2b(ea.x + fa1.x + fa2.x);
  o.h[1] = f2b(ea.y + fa1.y + fa2.y);
  o.h[2] = f2b(ea.z + fa1.z + fa2.z);
  o.h[3] = f2b(ea.w + fa1.w + fa2.w);
  o.h[4] = f2b(eb.x + fb1.x + fb2.x);
  o.h[5] = f2b(eb.y + fb1.y + fb2.y);
  o.h[6] = f2b(eb.z + fb1.z + fb2.z);
  o.h[7] = f2b(eb.w + fb1.w + fb2.w);
  *(uint4*)(S + b8) = o.v;
}

// ---------------- link scores: (1/9) * dot(S_p, S_t) ------------------------
// 16 lanes per pair, 4 dims each via uint2.
__global__ void score_kernel(const int* __restrict__ ell_pl,
                             const int* __restrict__ ell_tr,
                             const uint16_t* __restrict__ S,
                             float* __restrict__ out, int EP, int NP) {
  long g = (long)blockIdx.x * blockDim.x + threadIdx.x;
  long pair = g >> 4;
  int c = (int)(g & 15);
  if (pair >= EP) return;
  int p = ell_pl[pair];
  int t = ell_tr[pair];
  uint2 vp = *(const uint2*)(S + (size_t)p * 64 + c * 4);
  uint2 vt = *(const uint2*)(S + (size_t)(NP + t) * 64 + c * 4);
  f32x4 sp = unpack4(vp), st = unpack4(vt);
  float partial = sp.x * st.x + sp.y * st.y + sp.z * st.z + sp.w * st.w;
  partial += __shfl_xor(partial, 1);
  partial += __shfl_xor(partial, 2);
  partial += __shfl_xor(partial, 4);
  partial += __shfl_xor(partial, 8);
  if (c == 0) out[pair] = partial * (1.0f / 9.0f);
}

extern "C" void kernel_launch(void* const* d_in, const int* in_sizes, int n_in,
                              void* d_out, int out_size, void* d_ws, size_t ws_size,
                              hipStream_t stream) {
  const float* emb_pl = (const float*)d_in[0];
  const float* emb_tr = (const float*)d_in[1];
  const float* W_rel = (const float*)d_in[2];   // [L,2,64,64] f32
  const float* W_root = (const float*)d_in[3];  // [L,64,64] f32
  const float* bias = (const float*)d_in[4];    // [L,64] f32
  const int* pt_src = (const int*)d_in[7];
  const int* pt_dst = (const int*)d_in[8];
  const int* tp_src = (const int*)d_in[9];
  const int* tp_dst = (const int*)d_in[10];
  const int* ell_pl = (const int*)d_in[11];
  const int* ell_tr = (const int*)d_in[12];
  float* out = (float*)d_out;

  const int NP = in_sizes[5];
  const int NT = in_sizes[6];
  const int E = in_sizes[7];
  const int EP = in_sizes[11];
  const int N = NP + NT;
  const long TE = 2L * E;
  const int NB = (N + BN - 1) / BN;

  char* ws = (char*)d_ws;
  size_t off = 0;
  uint16_t* agg = (uint16_t*)(ws + off); off += (size_t)N * 64 * 2;   // bf16; S later
  uint16_t* x1  = (uint16_t*)(ws + off); off += (size_t)N * 64 * 2;   // bf16
  uint16_t* x2  = (uint16_t*)(ws + off); off += (size_t)N * 64 * 2;   // bf16 (xb0 early)
  uint32_t* pk  = (uint32_t*)(ws + off); off += (size_t)TE * 4;
  int* col      = (int*)(ws + off);      off += (size_t)TE * 4;
  int* rowptr   = (int*)(ws + off);      off += (size_t)(N + 1) * 4;
  int* bucketCount = (int*)(ws + off);   off += (size_t)NB * 4;
  int* bucketStart = (int*)(ws + off);   off += (size_t)NB * 4;
  int* gCursor     = (int*)(ws + off);   off += (size_t)NB * 4;

  uint16_t* xb0 = x2;  // x2 slot doubles as bf16 embedding copy until transform1
  uint16_t* S = agg;   // agg slot reused for node sums after transform1

  const int TB = 256;
  const int PB = 256;  // partition blocks
  int chunk = (int)((TE + PB - 1) / PB);
  long cvt = ((long)N * 64 / 8 + TB - 1) / TB;
  int pullBlocks = (N + 15) / 16;
  int scoreBlocks = (int)(((long)EP * 16 + TB - 1) / TB);
  const int BP = 256, GT = 1024;  // transform grid split

  // ---- bf16 embedding copy (used by pull0 + transform0) ----
  convert_kernel<<<(int)cvt, TB, 0, stream>>>(emb_pl, emb_tr, xb0, NP, N);

  // ---- bucket build (once; reused by both layers) ----
  hipMemsetAsync(bucketCount, 0, (size_t)NB * 4, stream);
  bucket_hist_kernel<<<128, TB, NB * 4, stream>>>(pt_dst, tp_dst, bucketCount,
                                                  E, NP, NB);
  bucket_scan_kernel<<<1, 1024, 0, stream>>>(bucketCount, bucketStart, gCursor, NB);
  partition_kernel<<<PB, 512, 2 * NB * 4, stream>>>(
      pt_src, pt_dst, tp_src, tp_dst, gCursor, pk, E, NP, NB, chunk);
  local_csr_kernel<<<NB, TB, 0, stream>>>(bucketStart, bucketCount, pk,
                                          rowptr, col, N, (int)TE);

  // ---- layer 0 (x = bf16 embedding copy, global indexing) ----
  pull_kernel<<<pullBlocks, TB, 0, stream>>>(rowptr, col, xb0, agg, N);
  transform_kernel<<<GT, TB, 0, stream>>>(
      xb0, xb0 + (size_t)NP * 64, agg, W_root + 0 * 4096, W_rel + 1 * 4096,
      W_rel + 0 * 4096, bias + 0, x1, NP, NT, BP);

  // ---- layer 1 (x = x1) ----
  pull_kernel<<<pullBlocks, TB, 0, stream>>>(rowptr, col, x1, agg, N);
  transform_kernel<<<GT, TB, 0, stream>>>(
      x1, x1 + (size_t)NP * 64, agg, W_root + 1 * 4096, W_rel + 3 * 4096,
      W_rel + 2 * 4096, bias + 64, x2, NP, NT, BP);

  // ---- node sums S = emb + x1 + x2, then link scores ----
  sum_kernel<<<(int)cvt, TB, 0, stream>>>(emb_pl, emb_tr, x1, x2, S, NP, N);
  score_kernel<<<scoreBlocks, TB, 0, stream>>>(ell_pl, ell_tr, S, out, EP, NP);
}

// Round 8
// 592.237 us; speedup vs baseline: 5.2805x; 1.0490x over previous
//
#include <hip/hip_runtime.h>
#include <stdint.h>

typedef __attribute__((ext_vector_type(8))) short bf16x8;
typedef __attribute__((ext_vector_type(4))) float f32x4;

#define BN 192  // dst nodes per bucket (fits 256-wide LDS scan)

static __device__ __forceinline__ float b2f_lo(uint32_t w) {
  union { uint32_t u; float f; } c; c.u = w << 16; return c.f;
}
static __device__ __forceinline__ float b2f_hi(uint32_t w) {
  union { uint32_t u; float f; } c; c.u = w & 0xffff0000u; return c.f;
}
static __device__ __forceinline__ uint16_t f2b(float f) {
  union { float f; uint32_t u; } c; c.f = f;
  return (uint16_t)((c.u + 0x7fffu + ((c.u >> 16) & 1u)) >> 16);
}
static __device__ __forceinline__ f32x4 unpack4(uint2 t) {
  f32x4 r;
  r.x = b2f_lo(t.x); r.y = b2f_hi(t.x);
  r.z = b2f_lo(t.y); r.w = b2f_hi(t.y);
  return r;
}
static __device__ __forceinline__ void acc8(float* s, uint4 v) {
  s[0] += b2f_lo(v.x); s[1] += b2f_hi(v.x);
  s[2] += b2f_lo(v.y); s[3] += b2f_hi(v.y);
  s[4] += b2f_lo(v.z); s[5] += b2f_hi(v.z);
  s[6] += b2f_lo(v.w); s[7] += b2f_hi(v.w);
}

// ---------------- fp32 -> bf16 embedding conversion (into xb buffer) --------
__global__ __launch_bounds__(256) void convert_kernel(
    const float* __restrict__ emb_pl, const float* __restrict__ emb_tr,
    uint16_t* __restrict__ xb, int NP, int N) {
  long g = (long)blockIdx.x * 256 + threadIdx.x;
  long base8 = g * 8;
  long total = (long)N * 64;
  if (base8 >= total) return;
  long plEnd = (long)NP * 64;  // divisible by 8, no straddle
  const float* src = (base8 < plEnd) ? (emb_pl + base8) : (emb_tr + (base8 - plEnd));
  f32x4 a = *(const f32x4*)src;
  f32x4 b = *(const f32x4*)(src + 4);
  union { uint16_t h[8]; uint4 v; } o;
  o.h[0] = f2b(a.x); o.h[1] = f2b(a.y); o.h[2] = f2b(a.z); o.h[3] = f2b(a.w);
  o.h[4] = f2b(b.x); o.h[5] = f2b(b.y); o.h[6] = f2b(b.z); o.h[7] = f2b(b.w);
  *(uint4*)(xb + base8) = o.v;
}

// ---------------- bucket histogram over dst (both relations) ----------------
__global__ __launch_bounds__(256) void bucket_hist_kernel(
    const int* __restrict__ pt_dst, const int* __restrict__ tp_dst,
    int* __restrict__ bucketCount, int E, int NP, int NB) {
  extern __shared__ int hist[];
  int t = threadIdx.x;
  for (int b = t; b < NB; b += 256) hist[b] = 0;
  __syncthreads();
  long total = 2L * E;
  long stride = (long)gridDim.x * 256;
  for (long e = (long)blockIdx.x * 256 + t; e < total; e += stride) {
    int dstG = (e < E) ? (NP + pt_dst[e]) : tp_dst[e - E];
    atomicAdd(&hist[dstG / BN], 1);
  }
  __syncthreads();
  for (int b = t; b < NB; b += 256) {
    int h = hist[b];
    if (h > 0) atomicAdd(&bucketCount[b], h);
  }
}

// ---------------- exclusive scan of bucket counts (1 block) -----------------
__global__ __launch_bounds__(1024) void bucket_scan_kernel(
    const int* __restrict__ bucketCount, int* __restrict__ bucketStart,
    int* __restrict__ gCursor, int NB) {
  __shared__ int s[1024];
  int t = threadIdx.x;
  int K = (NB + 1023) >> 10;
  int b0 = t * K;
  int local = 0;
  for (int j = 0; j < K; ++j) {
    int b = b0 + j;
    if (b < NB) local += bucketCount[b];
  }
  int acc = local;
  s[t] = local;
  __syncthreads();
  for (int off = 1; off < 1024; off <<= 1) {
    int u = (t >= off) ? s[t - off] : 0;
    __syncthreads();
    acc += u;
    s[t] = acc;
    __syncthreads();
  }
  int run = acc - local;  // exclusive prefix of this thread's chunk
  for (int j = 0; j < K; ++j) {
    int b = b0 + j;
    if (b < NB) {
      bucketStart[b] = run;
      gCursor[b] = run;
      run += bucketCount[b];
    }
  }
}

// ---------------- partition: pk[slot] = (dl<<20)|srcGlobal ------------------
__global__ __launch_bounds__(512) void partition_kernel(
    const int* __restrict__ pt_src, const int* __restrict__ pt_dst,
    const int* __restrict__ tp_src, const int* __restrict__ tp_dst,
    int* __restrict__ gCursor, uint32_t* __restrict__ pk,
    int E, int NP, int NB, int chunk) {
  extern __shared__ int lds[];
  int* hist = lds;        // [NB]
  int* base = lds + NB;   // [NB]
  int t = threadIdx.x;
  long e0 = (long)blockIdx.x * chunk;
  long e1 = e0 + chunk;
  long total = 2L * E;
  if (e1 > total) e1 = total;
  for (int b = t; b < NB; b += 512) hist[b] = 0;
  __syncthreads();
  for (long e = e0 + t; e < e1; e += 512) {
    int dstG = (e < E) ? (NP + pt_dst[e]) : tp_dst[e - E];
    atomicAdd(&hist[dstG / BN], 1);
  }
  __syncthreads();
  for (int b = t; b < NB; b += 512) {
    int h = hist[b];
    base[b] = (h > 0) ? atomicAdd(&gCursor[b], h) : 0;
    hist[b] = 0;  // reuse as local cursor
  }
  __syncthreads();
  for (long e = e0 + t; e < e1; e += 512) {
    int dstG, src;
    if (e < E) {
      dstG = NP + pt_dst[e];
      src = pt_src[e];
    } else {
      dstG = tp_dst[e - E];
      src = NP + tp_src[e - E];
    }
    int b = dstG / BN;
    int dl = dstG - b * BN;
    int pos = base[b] + atomicAdd(&hist[b], 1);
    pk[pos] = ((uint32_t)dl << 20) | (uint32_t)src;
  }
}

// ---------------- per-bucket counting sort -> node-grouped CSR --------------
__global__ __launch_bounds__(256) void local_csr_kernel(
    const int* __restrict__ bucketStart, const int* __restrict__ bucketCount,
    const uint32_t* __restrict__ pk, int* __restrict__ rowptr,
    int* __restrict__ col, int N, int TEtotal) {
  __shared__ int hist[256];
  __shared__ int cur[256];
  int t = threadIdx.x;
  int b = blockIdx.x;
  hist[t] = 0;
  __syncthreads();
  int beg = bucketStart[b], num = bucketCount[b];
  for (int i = t; i < num; i += 256)
    atomicAdd(&hist[pk[beg + i] >> 20], 1);
  __syncthreads();
  int v = hist[t];
  int acc = v;
  cur[t] = v;
  __syncthreads();
  for (int off = 1; off < 256; off <<= 1) {
    int u = (t >= off) ? cur[t - off] : 0;
    __syncthreads();
    acc += u;
    cur[t] = acc;
    __syncthreads();
  }
  int excl = acc - v;
  int node = b * BN + t;
  if (t < BN && node < N) rowptr[node] = beg + excl;
  cur[t] = excl;
  __syncthreads();
  for (int i = t; i < num; i += 256) {
    uint32_t w = pk[beg + i];
    int dl = (int)(w >> 20);
    int pos = atomicAdd(&cur[dl], 1);
    col[beg + pos] = (int)(w & 0xFFFFFu);
  }
  if (b == 0 && t == 0) rowptr[N] = TEtotal;
}

// ---------------- pull aggregation: agg[n] = bf16(mean of src rows) ---------
// 8 lanes per node (8 nodes/wave), lane handles 8 dims via one uint4 (16 B).
__global__ __launch_bounds__(256) void pull_kernel(
    const int* __restrict__ rowptr, const int* __restrict__ col,
    const uint16_t* __restrict__ base, uint16_t* __restrict__ agg, int N) {
  int node = blockIdx.x * 32 + (threadIdx.x >> 3);
  int c = threadIdx.x & 7;  // dims 8c..8c+7
  if (node >= N) return;
  int beg = rowptr[node], end = rowptr[node + 1];
  float s[8] = {0, 0, 0, 0, 0, 0, 0, 0};
  const uint16_t* bp = base + c * 8;
  int i = beg;
  for (; i + 4 <= end; i += 4) {
    int c0 = col[i], c1 = col[i + 1], c2 = col[i + 2], c3 = col[i + 3];
    uint4 v0 = *(const uint4*)(bp + (size_t)c0 * 64);
    uint4 v1 = *(const uint4*)(bp + (size_t)c1 * 64);
    uint4 v2 = *(const uint4*)(bp + (size_t)c2 * 64);
    uint4 v3 = *(const uint4*)(bp + (size_t)c3 * 64);
    acc8(s, v0); acc8(s, v1); acc8(s, v2); acc8(s, v3);
  }
  for (; i < end; ++i)
    acc8(s, *(const uint4*)(bp + (size_t)col[i] * 64));
  int deg = end - beg;
  float inv = 1.0f / (float)(deg > 1 ? deg : 1);
  union { uint16_t h[8]; uint4 v; } o;
#pragma unroll
  for (int j = 0; j < 8; ++j) o.h[j] = f2b(s[j] * inv);
  *(uint4*)(agg + (size_t)node * 64 + c * 8) = o.v;
}

// ---------------- fused transform: xout = relu(x@Wroot + agg@Wrel + b) ------
__global__ __launch_bounds__(256) void transform_kernel(
    const uint16_t* __restrict__ xpl, const uint16_t* __restrict__ xtr,
    const uint16_t* __restrict__ agg,
    const float* __restrict__ Wroot,
    const float* __restrict__ WrelP, const float* __restrict__ WrelT,
    const float* __restrict__ biasrow,
    uint16_t* __restrict__ xout, int NP, int NT, int BP) {
  int wave = threadIdx.x >> 6;
  int lane = threadIdx.x & 63;
  int m = lane & 15, q = lane >> 4;

  int wl, nw, ntiles, nodeBase;
  const uint16_t* xbase;
  const float* Wrel;
  if ((int)blockIdx.x < BP) {
    wl = blockIdx.x * 4 + wave; nw = BP * 4; ntiles = NP / 16;
    xbase = xpl; Wrel = WrelP; nodeBase = 0;
  } else {
    wl = (blockIdx.x - BP) * 4 + wave; nw = (gridDim.x - BP) * 4; ntiles = NT / 16;
    xbase = xtr; Wrel = WrelT; nodeBase = NP;
  }

  // B fragments: B[k][n], lane n=16*ct+m, elems k=32*kc+8*q+i
  bf16x8 br[2][4], bl[2][4];
  for (int kc = 0; kc < 2; ++kc)
    for (int ct = 0; ct < 4; ++ct) {
      int n = 16 * ct + m;
      int k0 = 32 * kc + 8 * q;
      bf16x8 t0, t1;
      for (int i = 0; i < 8; ++i) {
        t0[i] = (short)f2b(Wroot[(size_t)(k0 + i) * 64 + n]);
        t1[i] = (short)f2b(Wrel[(size_t)(k0 + i) * 64 + n]);
      }
      br[kc][ct] = t0;
      bl[kc][ct] = t1;
    }
  float bv[4];
  for (int ct = 0; ct < 4; ++ct) bv[ct] = biasrow[16 * ct + m];

  for (int t = wl; t < ntiles; t += nw) {
    int rowLocal = t * 16 + m;  // A row: m = lane&15
    int nodeG = nodeBase + rowLocal;
    const uint16_t* xrow = xbase + (size_t)rowLocal * 64;
    bf16x8 ax0 = *(const bf16x8*)(xrow + 8 * q);
    bf16x8 ax1 = *(const bf16x8*)(xrow + 32 + 8 * q);

    const uint16_t* arow = agg + (size_t)nodeG * 64;
    bf16x8 aa0 = *(const bf16x8*)(arow + 8 * q);
    bf16x8 aa1 = *(const bf16x8*)(arow + 32 + 8 * q);

    f32x4 acc[4];
#pragma unroll
    for (int ct = 0; ct < 4; ++ct) acc[ct] = (f32x4){bv[ct], bv[ct], bv[ct], bv[ct]};
#pragma unroll
    for (int ct = 0; ct < 4; ++ct) {
      acc[ct] = __builtin_amdgcn_mfma_f32_16x16x32_bf16(ax0, br[0][ct], acc[ct], 0, 0, 0);
      acc[ct] = __builtin_amdgcn_mfma_f32_16x16x32_bf16(ax1, br[1][ct], acc[ct], 0, 0, 0);
      acc[ct] = __builtin_amdgcn_mfma_f32_16x16x32_bf16(aa0, bl[0][ct], acc[ct], 0, 0, 0);
      acc[ct] = __builtin_amdgcn_mfma_f32_16x16x32_bf16(aa1, bl[1][ct], acc[ct], 0, 0, 0);
    }
    // D: row = 4*q + r, col = 16*ct + m
    int nodeRow0 = nodeBase + t * 16;
#pragma unroll
    for (int ct = 0; ct < 4; ++ct)
#pragma unroll
      for (int r = 0; r < 4; ++r) {
        float v = acc[ct][r];
        v = v > 0.0f ? v : 0.0f;
        xout[(size_t)(nodeRow0 + 4 * q + r) * 64 + 16 * ct + m] = f2b(v);
      }
  }
}

// ---------------- node sums: S = bf16(emb + x1 + x2) ------------------------
__global__ __launch_bounds__(256) void sum_kernel(
    const float* __restrict__ emb_pl, const float* __restrict__ emb_tr,
    const uint16_t* __restrict__ x1, const uint16_t* __restrict__ x2,
    uint16_t* __restrict__ S, int NP, int N) {
  long g = (long)blockIdx.x * 256 + threadIdx.x;
  long b8 = g * 8;
  long total = (long)N * 64;
  if (b8 >= total) return;
  long plEnd = (long)NP * 64;
  const float* e = (b8 < plEnd) ? (emb_pl + b8) : (emb_tr + (b8 - plEnd));
  f32x4 ea = *(const f32x4*)e;
  f32x4 eb = *(const f32x4*)(e + 4);
  uint4 x1v = *(const uint4*)(x1 + b8);
  uint4 x2v = *(const uint4*)(x2 + b8);
  f32x4 fa1 = unpack4(make_uint2(x1v.x, x1v.y)), fb1 = unpack4(make_uint2(x1v.z, x1v.w));
  f32x4 fa2 = unpack4(make_uint2(x2v.x, x2v.y)), fb2 = unpack4(make_uint2(x2v.z, x2v.w));
  union { uint16_t h[8]; uint4 v; } o;
  o.h[0] = f2b(ea.x + fa1.x + fa2.x);
  o.h[1] = f2b(ea.y + fa1.y + fa2.y);
  o.h[2] = f2b(ea.z + fa1.z + fa2.z);
  o.h[3] = f2b(ea.w + fa1.w + fa2.w);
  o.h[4] = f2b(eb.x + fb1.x + fb2.x);
  o.h[5] = f2b(eb.y + fb1.y + fb2.y);
  o.h[6] = f2b(eb.z + fb1.z + fb2.z);
  o.h[7] = f2b(eb.w + fb1.w + fb2.w);
  *(uint4*)(S + b8) = o.v;
}

// ---------------- link scores: (1/9) * dot(S_p, S_t) ------------------------
// 8 lanes per pair, 8 dims each via uint4 (16 B).
__global__ void score_kernel(const int* __restrict__ ell_pl,
                             const int* __restrict__ ell_tr,
                             const uint16_t* __restrict__ S,
                             float* __restrict__ out, int EP, int NP) {
  long g = (long)blockIdx.x * blockDim.x + threadIdx.x;
  long pair = g >> 3;
  int c = (int)(g & 7);
  if (pair >= EP) return;
  int p = ell_pl[pair];
  int t = ell_tr[pair];
  uint4 vp = *(const uint4*)(S + (size_t)p * 64 + c * 8);
  uint4 vt = *(const uint4*)(S + (size_t)(NP + t) * 64 + c * 8);
  float partial = b2f_lo(vp.x) * b2f_lo(vt.x) + b2f_hi(vp.x) * b2f_hi(vt.x)
                + b2f_lo(vp.y) * b2f_lo(vt.y) + b2f_hi(vp.y) * b2f_hi(vt.y)
                + b2f_lo(vp.z) * b2f_lo(vt.z) + b2f_hi(vp.z) * b2f_hi(vt.z)
                + b2f_lo(vp.w) * b2f_lo(vt.w) + b2f_hi(vp.w) * b2f_hi(vt.w);
  partial += __shfl_xor(partial, 1);
  partial += __shfl_xor(partial, 2);
  partial += __shfl_xor(partial, 4);
  if (c == 0) out[pair] = partial * (1.0f / 9.0f);
}

extern "C" void kernel_launch(void* const* d_in, const int* in_sizes, int n_in,
                              void* d_out, int out_size, void* d_ws, size_t ws_size,
                              hipStream_t stream) {
  const float* emb_pl = (const float*)d_in[0];
  const float* emb_tr = (const float*)d_in[1];
  const float* W_rel = (const float*)d_in[2];   // [L,2,64,64] f32
  const float* W_root = (const float*)d_in[3];  // [L,64,64] f32
  const float* bias = (const float*)d_in[4];    // [L,64] f32
  const int* pt_src = (const int*)d_in[7];
  const int* pt_dst = (const int*)d_in[8];
  const int* tp_src = (const int*)d_in[9];
  const int* tp_dst = (const int*)d_in[10];
  const int* ell_pl = (const int*)d_in[11];
  const int* ell_tr = (const int*)d_in[12];
  float* out = (float*)d_out;

  const int NP = in_sizes[5];
  const int NT = in_sizes[6];
  const int E = in_sizes[7];
  const int EP = in_sizes[11];
  const int N = NP + NT;
  const long TE = 2L * E;
  const int NB = (N + BN - 1) / BN;

  char* ws = (char*)d_ws;
  size_t off = 0;
  uint16_t* agg = (uint16_t*)(ws + off); off += (size_t)N * 64 * 2;   // bf16; S later
  uint16_t* x1  = (uint16_t*)(ws + off); off += (size_t)N * 64 * 2;   // bf16
  uint16_t* x2  = (uint16_t*)(ws + off); off += (size_t)N * 64 * 2;   // bf16 (xb0 early)
  uint32_t* pk  = (uint32_t*)(ws + off); off += (size_t)TE * 4;
  int* col      = (int*)(ws + off);      off += (size_t)TE * 4;
  int* rowptr   = (int*)(ws + off);      off += (size_t)(N + 1) * 4;
  int* bucketCount = (int*)(ws + off);   off += (size_t)NB * 4;
  int* bucketStart = (int*)(ws + off);   off += (size_t)NB * 4;
  int* gCursor     = (int*)(ws + off);   off += (size_t)NB * 4;

  uint16_t* xb0 = x2;  // x2 slot doubles as bf16 embedding copy until transform1
  uint16_t* S = agg;   // agg slot reused for node sums after transform1

  const int TB = 256;
  const int PB = 256;  // partition blocks
  int chunk = (int)((TE + PB - 1) / PB);
  long cvt = ((long)N * 64 / 8 + TB - 1) / TB;
  int pullBlocks = (N + 31) / 32;
  int scoreBlocks = (int)(((long)EP * 8 + TB - 1) / TB);
  const int BP = 256, GT = 1024;  // transform grid split

  // ---- bf16 embedding copy (used by pull0 + transform0) ----
  convert_kernel<<<(int)cvt, TB, 0, stream>>>(emb_pl, emb_tr, xb0, NP, N);

  // ---- bucket build (once; reused by both layers) ----
  hipMemsetAsync(bucketCount, 0, (size_t)NB * 4, stream);
  bucket_hist_kernel<<<128, TB, NB * 4, stream>>>(pt_dst, tp_dst, bucketCount,
                                                  E, NP, NB);
  bucket_scan_kernel<<<1, 1024, 0, stream>>>(bucketCount, bucketStart, gCursor, NB);
  partition_kernel<<<PB, 512, 2 * NB * 4, stream>>>(
      pt_src, pt_dst, tp_src, tp_dst, gCursor, pk, E, NP, NB, chunk);
  local_csr_kernel<<<NB, TB, 0, stream>>>(bucketStart, bucketCount, pk,
                                          rowptr, col, N, (int)TE);

  // ---- layer 0 (x = bf16 embedding copy, global indexing) ----
  pull_kernel<<<pullBlocks, TB, 0, stream>>>(rowptr, col, xb0, agg, N);
  transform_kernel<<<GT, TB, 0, stream>>>(
      xb0, xb0 + (size_t)NP * 64, agg, W_root + 0 * 4096, W_rel + 1 * 4096,
      W_rel + 0 * 4096, bias + 0, x1, NP, NT, BP);

  // ---- layer 1 (x = x1) ----
  pull_kernel<<<pullBlocks, TB, 0, stream>>>(rowptr, col, x1, agg, N);
  transform_kernel<<<GT, TB, 0, stream>>>(
      x1, x1 + (size_t)NP * 64, agg, W_root + 1 * 4096, W_rel + 3 * 4096,
      W_rel + 2 * 4096, bias + 64, x2, NP, NT, BP);

  // ---- node sums S = emb + x1 + x2, then link scores ----
  sum_kernel<<<(int)cvt, TB, 0, stream>>>(emb_pl, emb_tr, x1, x2, S, NP, N);
  score_kernel<<<scoreBlocks, TB, 0, stream>>>(ell_pl, ell_tr, S, out, EP, NP);
}